// Round 4
// baseline (1886.049 us; speedup 1.0000x reference)
//
#include <hip/hip_runtime.h>
#include <hip/hip_bf16.h>

// Problem constants (from reference)
#define NN 100000          // nodes
#define NE 1600000         // edges
#define NR 20              // relations
#define NRX 21             // + self-loop pseudo-relation
#define FD 32              // feature dim (in = hidden = out = 32)
#define ETOT (NE + NN)     // edges + self-loop virtual edges = 1,700,000
#define MKEYS (NRX * NN)   // sort buckets = 2,100,000
#define CHUNK 32           // edges per half-wave task
#define NCHUNK (ETOT / CHUNK)  // 53,125 (divides exactly)

static_assert(ETOT % CHUNK == 0, "chunking must be exact");

// -------- W basis combine, TRANSPOSED output: Wt[r][o][i] = W[r][i][o] ------
// Wt layout lets lane o load its column as 128 contiguous bytes (coalesced).
__global__ void k_w(const float* __restrict__ V1, const float* __restrict__ a1,
                    const float* __restrict__ lp1,
                    const float* __restrict__ V2, const float* __restrict__ a2,
                    const float* __restrict__ lp2,
                    float* __restrict__ Wt1, float* __restrict__ Wt2) {
  int t = blockIdx.x * 256 + threadIdx.x;
  if (t >= 2 * NRX * FD * FD) return;
  int l = t / (NRX * FD * FD);
  int rest = t - l * (NRX * FD * FD);
  int r = rest / (FD * FD);
  int io = rest - r * (FD * FD);
  int o = io >> 5;        // output dim
  int i = io & 31;        // input dim
  const float* V = l ? V2 : V1;
  const float* a = l ? a2 : a1;
  const float* lp = l ? lp2 : lp1;
  float* Wt = l ? Wt2 : Wt1;
  float v;
  if (r == NR) {
    v = lp[i * FD + o];
  } else {
    v = 0.f;
#pragma unroll
    for (int b = 0; b < 8; ++b) v += a[r * 8 + b] * V[b * FD * FD + i * FD + o];
  }
  Wt[((r << 5) | o) * FD + i] = v;
}

// ---------------- histogram over keys (dst*NRX + rel) — dst-major -----------
__global__ void k_hist(const int* __restrict__ dst, const int* __restrict__ et,
                       int* __restrict__ hist) {
  int e = blockIdx.x * 256 + threadIdx.x;
  if (e < NE) {
    atomicAdd(&hist[dst[e] * NRX + et[e]], 1);
  } else if (e < ETOT) {
    atomicAdd(&hist[(e - NE) * NRX + NR], 1);  // self-loop bucket
  }
}

// ---------------- hierarchical exclusive scan (1024 elems / block) ----------
__global__ void k_scan1(int* __restrict__ data, int* __restrict__ aux, int n) {
  __shared__ int sd[256];
  int t = threadIdx.x, blk = blockIdx.x;
  int base = blk * 1024 + t * 4;
  int v[4];
#pragma unroll
  for (int j = 0; j < 4; ++j) v[j] = (base + j < n) ? data[base + j] : 0;
  int s = v[0] + v[1] + v[2] + v[3];
  sd[t] = s;
  __syncthreads();
  for (int off = 1; off < 256; off <<= 1) {
    int x = (t >= off) ? sd[t - off] : 0;
    __syncthreads();
    sd[t] += x;
    __syncthreads();
  }
  int run = sd[t] - s;  // exclusive prefix within block
  if (t == 255) aux[blk] = sd[255];
#pragma unroll
  for (int j = 0; j < 4; ++j) {
    if (base + j < n) { data[base + j] = run; run += v[j]; }
  }
}

__global__ void k_scan2(int* __restrict__ aux, int n) {  // single block, n<=2304
  __shared__ int sd[256];
  int t = threadIdx.x;
  int loc[9];
  int s = 0;
#pragma unroll
  for (int j = 0; j < 9; ++j) {
    int idx = t * 9 + j;
    int v = (idx < n) ? aux[idx] : 0;
    loc[j] = s;
    s += v;
  }
  sd[t] = s;
  __syncthreads();
  for (int off = 1; off < 256; off <<= 1) {
    int x = (t >= off) ? sd[t - off] : 0;
    __syncthreads();
    sd[t] += x;
    __syncthreads();
  }
  int excl = sd[t] - s;
#pragma unroll
  for (int j = 0; j < 9; ++j) {
    int idx = t * 9 + j;
    if (idx < n) aux[idx] = excl + loc[j];
  }
}

__global__ void k_scan3(int* __restrict__ data, const int* __restrict__ aux, int n) {
  int i = blockIdx.x * 256 + threadIdx.x;
  if (i < n) data[i] += aux[i >> 10];
}

// ---------------- scatter edges into (dst,rel)-sorted order -----------------
__global__ void k_scatter(const int* __restrict__ src, const int* __restrict__ dst,
                          const int* __restrict__ et, int* __restrict__ offs,
                          int2* __restrict__ es) {
  int e = blockIdx.x * 256 + threadIdx.x;
  if (e >= ETOT) return;
  int s, d, r;
  if (e < NE) { s = src[e]; d = dst[e]; r = et[e]; }
  else        { s = d = e - NE; r = NR; }
  int key = d * NRX + r;
  int pos = atomicAdd(&offs[key], 1);
  es[pos] = make_int2((s << 5) | r, d);
}

// ---------------- init h with bias broadcast --------------------------------
__global__ void k_init(float* __restrict__ h, const float* __restrict__ b) {
  int i = blockIdx.x * 256 + threadIdx.x;
  if (i < NN * FD) h[i] = b[i & (FD - 1)];
}

__global__ void k_relu(float* __restrict__ h) {
  int i = blockIdx.x * 256 + threadIdx.x;
  if (i < NN * FD) h[i] = fmaxf(h[i], 0.f);
}

// --------- message pass: dst-run accumulation, one atomic per run -----------
// Edges sorted by (dst, rel). A half-wave owns a 32-edge chunk; lane = output
// dim o. acc[o] accumulates across the same-dst run; W column reloaded from
// the transposed global table only when rel changes (~every 1.45 edges).
__global__ void __launch_bounds__(256) k_msg(const float* __restrict__ xin,
                                             const int2* __restrict__ es,
                                             const float* __restrict__ Wt,
                                             float* __restrict__ hout) {
  int hw = (blockIdx.x * 256 + threadIdx.x) >> 5;  // global half-wave id
  int o = threadIdx.x & 31;                        // output dim owned by lane
  int nhw = (gridDim.x * 256) >> 5;

  float Wr[32];
  for (int c = hw; c < NCHUNK; c += nhw) {
    int e0 = c * CHUNK;
    int rprev = -1, dprev = -1;
    float acc = 0.f;
    for (int ei = 0; ei < CHUNK; ++ei) {
      int2 md = es[e0 + ei];            // lane-uniform per half-wave
      int s = md.x >> 5;
      int r = md.x & 31;
      int d = md.y;
      if (d != dprev) {                 // dst-run boundary: flush accumulator
        if (dprev >= 0) unsafeAtomicAdd(&hout[(dprev << 5) | o], acc);
        acc = 0.f;
        dprev = d;
      }
      if (r != rprev) {                 // rel-run boundary: reload W column o
        rprev = r;
        const float4* wp = reinterpret_cast<const float4*>(Wt + (((r << 5) | o) << 5));
#pragma unroll
        for (int q = 0; q < 8; ++q) {
          float4 w = wp[q];
          Wr[q * 4 + 0] = w.x; Wr[q * 4 + 1] = w.y;
          Wr[q * 4 + 2] = w.z; Wr[q * 4 + 3] = w.w;
        }
      }
      const float4* xp = reinterpret_cast<const float4*>(xin) + s * 8;
      float a0 = 0.f, a1 = 0.f, a2 = 0.f, a3 = 0.f;
#pragma unroll
      for (int i4 = 0; i4 < 8; i4 += 4) {
        float4 x0 = xp[i4 + 0], x1 = xp[i4 + 1], x2 = xp[i4 + 2], x3 = xp[i4 + 3];
        a0 += x0.x * Wr[(i4 + 0) * 4 + 0] + x0.y * Wr[(i4 + 0) * 4 + 1] +
              x0.z * Wr[(i4 + 0) * 4 + 2] + x0.w * Wr[(i4 + 0) * 4 + 3];
        a1 += x1.x * Wr[(i4 + 1) * 4 + 0] + x1.y * Wr[(i4 + 1) * 4 + 1] +
              x1.z * Wr[(i4 + 1) * 4 + 2] + x1.w * Wr[(i4 + 1) * 4 + 3];
        a2 += x2.x * Wr[(i4 + 2) * 4 + 0] + x2.y * Wr[(i4 + 2) * 4 + 1] +
              x2.z * Wr[(i4 + 2) * 4 + 2] + x2.w * Wr[(i4 + 2) * 4 + 3];
        a3 += x3.x * Wr[(i4 + 3) * 4 + 0] + x3.y * Wr[(i4 + 3) * 4 + 1] +
              x3.z * Wr[(i4 + 3) * 4 + 2] + x3.w * Wr[(i4 + 3) * 4 + 3];
      }
      acc += (a0 + a1) + (a2 + a3);
    }
    unsafeAtomicAdd(&hout[(dprev << 5) | o], acc);  // flush last run of chunk
  }
}

// ---------------- launch ----------------------------------------------------
extern "C" void kernel_launch(void* const* d_in, const int* in_sizes, int n_in,
                              void* d_out, int out_size, void* d_ws, size_t ws_size,
                              hipStream_t stream) {
  const float* x   = (const float*)d_in[0];
  const int* src   = (const int*)d_in[1];
  const int* dst   = (const int*)d_in[2];
  const int* et    = (const int*)d_in[3];
  const float* V1  = (const float*)d_in[4];
  const float* a1  = (const float*)d_in[5];
  const float* lp1 = (const float*)d_in[6];
  const float* b1  = (const float*)d_in[7];
  const float* V2  = (const float*)d_in[8];
  const float* a2  = (const float*)d_in[9];
  const float* lp2 = (const float*)d_in[10];
  const float* b2  = (const float*)d_in[11];
  float* out = (float*)d_out;

  // workspace layout (bytes)
  char* w = (char*)d_ws;
  float* Wt1 = (float*)(w + 0);           //  86,016 B
  float* Wt2 = (float*)(w + 86016);       // ->   172,032
  int* hist = (int*)(w + 172032);         // 8,400,000 -> 8,572,032
  int* aux  = (int*)(w + 8572032);        //     8,204 -> (pad) 8,580,352
  int2* es  = (int2*)(w + 8580352);       // 13,600,000 -> 22,180,352
  float* h1 = (float*)(w + 22180352);     // 12,800,000 -> 34,980,352
  if (ws_size < 34980352) return;  // loud failure instead of corruption

  hipMemsetAsync(hist, 0, (size_t)MKEYS * 4, stream);

  k_w<<<(2 * NRX * FD * FD + 255) / 256, 256, 0, stream>>>(V1, a1, lp1, V2, a2, lp2, Wt1, Wt2);

  k_hist<<<(ETOT + 255) / 256, 256, 0, stream>>>(dst, et, hist);

  int nScanBlk = (MKEYS + 1023) / 1024;  // 2051
  k_scan1<<<nScanBlk, 256, 0, stream>>>(hist, aux, MKEYS);
  k_scan2<<<1, 256, 0, stream>>>(aux, nScanBlk);
  k_scan3<<<(MKEYS + 255) / 256, 256, 0, stream>>>(hist, aux, MKEYS);

  k_scatter<<<(ETOT + 255) / 256, 256, 0, stream>>>(src, dst, et, hist, es);

  k_init<<<(NN * FD + 255) / 256, 256, 0, stream>>>(h1, b1);
  k_init<<<(NN * FD + 255) / 256, 256, 0, stream>>>(out, b2);

  // layer 1: x -> h1
  k_msg<<<2048, 256, 0, stream>>>(x, es, Wt1, h1);
  k_relu<<<(NN * FD + 255) / 256, 256, 0, stream>>>(h1);
  // layer 2: relu(h1) -> out
  k_msg<<<2048, 256, 0, stream>>>(h1, es, Wt2, out);
}

// Round 6
// 1005.228 us; speedup vs baseline: 1.8762x; 1.8762x over previous
//
#include <hip/hip_runtime.h>
#include <hip/hip_bf16.h>

// Problem constants (from reference)
#define NN 100000          // nodes
#define NE 1600000         // edges
#define NR 20              // relations
#define NB 8               // bases
#define FD 32              // feature dim (in = hidden = out = 32)

// Basis trick: h[v] = sum_b ( sum_{e->v} a[r_e,b] x[src_e] ) @ V_b  + x[v]@W_loop + bias
//   edge phase:  z[v][b][i] += a[r][b] * x[s][i]   (8 scalars per edge, no W matrix)
//   finish GEMM: h[v][o] = bias[o] + sum_{k<256} z[v][k]*V[k*32+o] + sum_i x[v][i]*loop[i*32+o]
// z rows are exclusive per node (CSR, wave-per-node) -> NO atomics in the math path.

// ---------------- histogram over dst ----------------------------------------
__global__ void k_hist(const int* __restrict__ dst, int* __restrict__ hist) {
  int e = blockIdx.x * 256 + threadIdx.x;
  if (e < NE) atomicAdd(&hist[dst[e]], 1);
}

// ---------------- hierarchical exclusive scan (1024 elems / block) ----------
__global__ void k_scan1(int* __restrict__ data, int* __restrict__ aux, int n) {
  __shared__ int sd[256];
  int t = threadIdx.x, blk = blockIdx.x;
  int base = blk * 1024 + t * 4;
  int v[4];
#pragma unroll
  for (int j = 0; j < 4; ++j) v[j] = (base + j < n) ? data[base + j] : 0;
  int s = v[0] + v[1] + v[2] + v[3];
  sd[t] = s;
  __syncthreads();
  for (int off = 1; off < 256; off <<= 1) {
    int x = (t >= off) ? sd[t - off] : 0;
    __syncthreads();
    sd[t] += x;
    __syncthreads();
  }
  int run = sd[t] - s;
  if (t == 255) aux[blk] = sd[255];
#pragma unroll
  for (int j = 0; j < 4; ++j) {
    if (base + j < n) { data[base + j] = run; run += v[j]; }
  }
}

__global__ void k_scan2(int* __restrict__ aux, int n) {  // single block, n<=2304
  __shared__ int sd[256];
  int t = threadIdx.x;
  int loc[9];
  int s = 0;
#pragma unroll
  for (int j = 0; j < 9; ++j) {
    int idx = t * 9 + j;
    int v = (idx < n) ? aux[idx] : 0;
    loc[j] = s;
    s += v;
  }
  sd[t] = s;
  __syncthreads();
  for (int off = 1; off < 256; off <<= 1) {
    int x = (t >= off) ? sd[t - off] : 0;
    __syncthreads();
    sd[t] += x;
    __syncthreads();
  }
  int excl = sd[t] - s;
#pragma unroll
  for (int j = 0; j < 9; ++j) {
    int idx = t * 9 + j;
    if (idx < n) aux[idx] = excl + loc[j];
  }
}

__global__ void k_scan3(int* __restrict__ data, const int* __restrict__ aux, int n) {
  int i = blockIdx.x * 256 + threadIdx.x;
  if (i < n) data[i] += aux[i >> 10];
}

// ---------------- scatter edges into dst-sorted order (4 B records) ---------
__global__ void k_scatter(const int* __restrict__ src, const int* __restrict__ dst,
                          const int* __restrict__ et, int* __restrict__ offs,
                          int* __restrict__ es) {
  int e = blockIdx.x * 256 + threadIdx.x;
  if (e >= NE) return;
  int pos = atomicAdd(&offs[dst[e]], 1);
  es[pos] = (src[e] << 5) | et[e];
}
// After scatter: offs[v] = end of row v; start = (v==0) ? 0 : offs[v-1].

// ---------------- edge phase: wave-per-node CSR aggregation ------------------
// lane l: i = l&31 (input dim), hh = l>>5 (basis half). Lane accumulates
// z[b][i] for b = 4*hh + {0,1,2,3}. Per edge: 1 rec + 1 x + 1 float4(a) + 4 FMA.
__global__ void __launch_bounds__(256) k_edge(const float* __restrict__ xin,
                                              const int* __restrict__ offs,
                                              const int* __restrict__ es,
                                              const float* __restrict__ arel,  // [20][8]
                                              float* __restrict__ z,           // [cap][256]
                                              int n0, int n1) {
  int wid = (blockIdx.x * 256 + threadIdx.x) >> 6;
  int nw  = (gridDim.x * 256) >> 6;
  int l = threadIdx.x & 63;
  int i = l & 31, hh = l >> 5;
  const float4* aT = reinterpret_cast<const float4*>(arel);
  for (int v = n0 + wid; v < n1; v += nw) {
    int e0 = (v == 0) ? 0 : offs[v - 1];
    int e1 = offs[v];
    float z0 = 0.f, z1 = 0.f, z2 = 0.f, z3 = 0.f;
    for (int e = e0; e < e1; ++e) {
      int rec = es[e];                      // lane-uniform
      int s = rec >> 5, r = rec & 31;
      float xv = xin[(s << 5) | i];         // coalesced 128 B per half-wave
      float4 av = aT[(r << 1) | hh];        // uniform per half, 640 B L1 table
      z0 += av.x * xv; z1 += av.y * xv; z2 += av.z * xv; z3 += av.w * xv;
    }
    float* zp = z + ((size_t)(v - n0) << 8) + (hh << 7) + i;  // [vloc][b][i]
    zp[0] = z0; zp[32] = z1; zp[64] = z2; zp[96] = z3;        // b = 4hh+{0..3}
  }
}

// ---------------- finish GEMM: [cnt,288] @ [288,32] + bias (+relu) ----------
// block = 256 thr = 32 nodes: thread (o = tid&31, g = tid>>5) -> 4 nodes.
// V (8 KFLOATS) + loop (1 K) staged in LDS; Vl[k][o] reads are conflict-free.
__global__ void __launch_bounds__(256) k_finish(const float* __restrict__ z,
                                                const float* __restrict__ xin,
                                                const float* __restrict__ V,    // [8][32][32]
                                                const float* __restrict__ lp,   // [32][32]
                                                const float* __restrict__ bias, // [32]
                                                float* __restrict__ hout,
                                                int n0, int n1, int do_relu) {
  __shared__ float Vl[288 * 32];
  __shared__ float bl[32];
  int tid = threadIdx.x;
  {
    const float4* v4 = reinterpret_cast<const float4*>(V);
    const float4* l4 = reinterpret_cast<const float4*>(lp);
    float4* d4 = reinterpret_cast<float4*>(Vl);
    for (int t = tid; t < 2048; t += 256) d4[t] = v4[t];          // V rows 0..255
    if (tid < 256) d4[2048 + tid] = l4[tid];                      // loop rows 256..287
    if (tid < 32) bl[tid] = bias[tid];
  }
  __syncthreads();
  int o = tid & 31, g = tid >> 5;
  int base = n0 + blockIdx.x * 32 + g * 4;
  float acc[4];
  const float4* zp[4];
  const float4* xp[4];
  int valid[4];
#pragma unroll
  for (int j = 0; j < 4; ++j) {
    int n = base + j;
    valid[j] = (n < n1);
    int nc = valid[j] ? n : n1 - 1;
    zp[j] = reinterpret_cast<const float4*>(z + ((size_t)(nc - n0) << 8));
    xp[j] = reinterpret_cast<const float4*>(xin + ((size_t)nc << 5));
    acc[j] = bl[o];
  }
  for (int k4 = 0; k4 < 64; ++k4) {          // z part: k = 0..255
    int k = k4 << 2;
    float w0 = Vl[(k + 0) * 32 + o], w1 = Vl[(k + 1) * 32 + o],
          w2 = Vl[(k + 2) * 32 + o], w3 = Vl[(k + 3) * 32 + o];
#pragma unroll
    for (int j = 0; j < 4; ++j) {
      float4 zv = zp[j][k4];
      acc[j] += zv.x * w0 + zv.y * w1 + zv.z * w2 + zv.w * w3;
    }
  }
#pragma unroll
  for (int k4 = 0; k4 < 8; ++k4) {           // self-loop part: rows 256..287
    int k = 256 + (k4 << 2);
    float w0 = Vl[(k + 0) * 32 + o], w1 = Vl[(k + 1) * 32 + o],
          w2 = Vl[(k + 2) * 32 + o], w3 = Vl[(k + 3) * 32 + o];
#pragma unroll
    for (int j = 0; j < 4; ++j) {
      float4 xv = xp[j][k4];
      acc[j] += xv.x * w0 + xv.y * w1 + xv.z * w2 + xv.w * w3;
    }
  }
#pragma unroll
  for (int j = 0; j < 4; ++j) {
    if (valid[j]) {
      float vv = do_relu ? fmaxf(acc[j], 0.f) : acc[j];
      hout[((size_t)(base + j) << 5) | o] = vv;   // coalesced 128 B
    }
  }
}

// ---------------- launch ----------------------------------------------------
extern "C" void kernel_launch(void* const* d_in, const int* in_sizes, int n_in,
                              void* d_out, int out_size, void* d_ws, size_t ws_size,
                              hipStream_t stream) {
  const float* x   = (const float*)d_in[0];
  const int* src   = (const int*)d_in[1];
  const int* dst   = (const int*)d_in[2];
  const int* et    = (const int*)d_in[3];
  const float* V1  = (const float*)d_in[4];
  const float* a1  = (const float*)d_in[5];
  const float* lp1 = (const float*)d_in[6];
  const float* b1  = (const float*)d_in[7];
  const float* V2  = (const float*)d_in[8];
  const float* a2  = (const float*)d_in[9];
  const float* lp2 = (const float*)d_in[10];
  const float* b2  = (const float*)d_in[11];
  float* out = (float*)d_out;

  // workspace layout (bytes)
  char* w = (char*)d_ws;
  int*   offs = (int*)(w + 0);                 //   400,000 B (NN ints)
  int*   aux  = (int*)(w + 400128);            //       512 B (98 ints)
  int*   es   = (int*)(w + 400640);            // 6,400,000 -> 6,800,640
  float* h1   = (float*)(w + 6800640);         // 12,800,000 -> 19,600,640
  const size_t Z_OFF = 19600640;
  if (ws_size < Z_OFF + (size_t)4096 * 1024) return;  // need >= 4096-node chunks
  int cap = (int)((ws_size - Z_OFF) / 1024);   // nodes per chunk (256 floats each)
  if (cap > NN) cap = NN;
  float* z = (float*)(w + Z_OFF);
  int nch = (NN + cap - 1) / cap;
  int cs  = (NN + nch - 1) / nch;              // equal-ish chunk size

  hipMemsetAsync(offs, 0, (size_t)NN * 4, stream);

  k_hist<<<(NE + 255) / 256, 256, 0, stream>>>(dst, offs);

  int nScanBlk = (NN + 1023) / 1024;  // 98
  k_scan1<<<nScanBlk, 256, 0, stream>>>(offs, aux, NN);
  k_scan2<<<1, 256, 0, stream>>>(aux, nScanBlk);
  k_scan3<<<(NN + 255) / 256, 256, 0, stream>>>(offs, aux, NN);

  k_scatter<<<(NE + 255) / 256, 256, 0, stream>>>(src, dst, et, offs, es);

  // layer 1: x -> h1 (relu);  layer 2: h1 -> out
  for (int c = 0; c < nch; ++c) {
    int n0 = c * cs, n1 = n0 + cs;
    if (n1 > NN) n1 = NN;
    int cnt = n1 - n0;
    k_edge<<<1024, 256, 0, stream>>>(x, offs, es, a1, z, n0, n1);
    k_finish<<<(cnt + 31) / 32, 256, 0, stream>>>(z, x, V1, lp1, b1, h1, n0, n1, 1);
  }
  for (int c = 0; c < nch; ++c) {
    int n0 = c * cs, n1 = n0 + cs;
    if (n1 > NN) n1 = NN;
    int cnt = n1 - n0;
    k_edge<<<1024, 256, 0, stream>>>(h1, offs, es, a2, z, n0, n1);
    k_finish<<<(cnt + 31) / 32, 256, 0, stream>>>(z, h1, V2, lp2, b2, out, n0, n1, 0);
  }
}

// Round 8
// 902.249 us; speedup vs baseline: 2.0904x; 1.1141x over previous
//
#include <hip/hip_runtime.h>
#include <hip/hip_bf16.h>

// Problem constants (from reference)
#define NN 100000          // nodes
#define NE 1600000         // edges
#define NR 20              // relations
#define NB 8               // bases
#define FD 32              // feature dim (in = hidden = out = 32)

// Basis trick: h[v] = sum_b ( sum_{e->v} a[r_e,b] x[src_e] ) @ V_b  + x[v]@W_loop + bias
//   edge phase:  z[v][b][i] += a[r][b] * x[s][i]   (8 scalars per edge, no W matrix)
//   finish GEMM: h[v][o] = bias[o] + sum_{k<256} z[v][k]*V[k*32+o] + sum_i x[v][i]*loop[i*32+o]
// z rows are exclusive per node (CSR, wave-per-node) -> NO atomics in the math path.

// ---------------- histogram over dst ----------------------------------------
__global__ void k_hist(const int* __restrict__ dst, int* __restrict__ hist) {
  int e = blockIdx.x * 256 + threadIdx.x;
  if (e < NE) atomicAdd(&hist[dst[e]], 1);
}

// ---------------- hierarchical exclusive scan (1024 elems / block) ----------
__global__ void k_scan1(int* __restrict__ data, int* __restrict__ aux, int n) {
  __shared__ int sd[256];
  int t = threadIdx.x, blk = blockIdx.x;
  int base = blk * 1024 + t * 4;
  int v[4];
#pragma unroll
  for (int j = 0; j < 4; ++j) v[j] = (base + j < n) ? data[base + j] : 0;
  int s = v[0] + v[1] + v[2] + v[3];
  sd[t] = s;
  __syncthreads();
  for (int off = 1; off < 256; off <<= 1) {
    int x = (t >= off) ? sd[t - off] : 0;
    __syncthreads();
    sd[t] += x;
    __syncthreads();
  }
  int run = sd[t] - s;
  if (t == 255) aux[blk] = sd[255];
#pragma unroll
  for (int j = 0; j < 4; ++j) {
    if (base + j < n) { data[base + j] = run; run += v[j]; }
  }
}

__global__ void k_scan2(int* __restrict__ aux, int n) {  // single block, n<=2304
  __shared__ int sd[256];
  int t = threadIdx.x;
  int loc[9];
  int s = 0;
#pragma unroll
  for (int j = 0; j < 9; ++j) {
    int idx = t * 9 + j;
    int v = (idx < n) ? aux[idx] : 0;
    loc[j] = s;
    s += v;
  }
  sd[t] = s;
  __syncthreads();
  for (int off = 1; off < 256; off <<= 1) {
    int x = (t >= off) ? sd[t - off] : 0;
    __syncthreads();
    sd[t] += x;
    __syncthreads();
  }
  int excl = sd[t] - s;
#pragma unroll
  for (int j = 0; j < 9; ++j) {
    int idx = t * 9 + j;
    if (idx < n) aux[idx] = excl + loc[j];
  }
}

__global__ void k_scan3(int* __restrict__ data, const int* __restrict__ aux, int n) {
  int i = blockIdx.x * 256 + threadIdx.x;
  if (i < n) data[i] += aux[i >> 10];
}

// ---------------- scatter edges into dst-sorted order (4 B records) ---------
__global__ void k_scatter(const int* __restrict__ src, const int* __restrict__ dst,
                          const int* __restrict__ et, int* __restrict__ offs,
                          int* __restrict__ es) {
  int e = blockIdx.x * 256 + threadIdx.x;
  if (e >= NE) return;
  int pos = atomicAdd(&offs[dst[e]], 1);
  es[pos] = (src[e] << 5) | et[e];
}
// After scatter: offs[v] = end of row v; start = (v==0) ? 0 : offs[v-1].

// ---------------- edge phase: wave-per-node CSR aggregation ------------------
// lane l: i = l&31 (input dim), hh = l>>5 (basis half). Lane accumulates
// z[b][i] for b = 4*hh + {0,1,2,3}. 4-edge batch -> 4 outstanding x loads.
__global__ void __launch_bounds__(256) k_edge(const float* __restrict__ xin,
                                              const int* __restrict__ offs,
                                              const int* __restrict__ es,
                                              const float* __restrict__ arel,  // [20][8]
                                              float* __restrict__ z,           // [cap][256]
                                              int n0, int n1) {
  int wid = (blockIdx.x * 256 + threadIdx.x) >> 6;
  int nw  = (gridDim.x * 256) >> 6;
  int l = threadIdx.x & 63;
  int i = l & 31, hh = l >> 5;
  const float4* aT = reinterpret_cast<const float4*>(arel);
  for (int v = n0 + wid; v < n1; v += nw) {
    int e0 = (v == 0) ? 0 : offs[v - 1];
    int e1 = offs[v];
    e0 = __builtin_amdgcn_readfirstlane(e0);   // wave-uniform CSR bounds
    e1 = __builtin_amdgcn_readfirstlane(e1);
    float z0 = 0.f, z1 = 0.f, z2 = 0.f, z3 = 0.f;
    int e = e0;
    for (; e + 4 <= e1; e += 4) {              // 4 independent x loads in flight
      int r0 = es[e], r1 = es[e + 1], r2 = es[e + 2], r3 = es[e + 3];
      float x0 = xin[((r0 >> 5) << 5) | i];
      float x1 = xin[((r1 >> 5) << 5) | i];
      float x2 = xin[((r2 >> 5) << 5) | i];
      float x3 = xin[((r3 >> 5) << 5) | i];
      float4 a0 = aT[((r0 & 31) << 1) | hh];
      float4 a1 = aT[((r1 & 31) << 1) | hh];
      float4 a2 = aT[((r2 & 31) << 1) | hh];
      float4 a3 = aT[((r3 & 31) << 1) | hh];
      z0 += a0.x * x0; z1 += a0.y * x0; z2 += a0.z * x0; z3 += a0.w * x0;
      z0 += a1.x * x1; z1 += a1.y * x1; z2 += a1.z * x1; z3 += a1.w * x1;
      z0 += a2.x * x2; z1 += a2.y * x2; z2 += a2.z * x2; z3 += a2.w * x2;
      z0 += a3.x * x3; z1 += a3.y * x3; z2 += a3.z * x3; z3 += a3.w * x3;
    }
    for (; e < e1; ++e) {                      // tail (<4 edges)
      int rec = es[e];
      int s = rec >> 5, r = rec & 31;
      float xv = xin[(s << 5) | i];
      float4 av = aT[(r << 1) | hh];
      z0 += av.x * xv; z1 += av.y * xv; z2 += av.z * xv; z3 += av.w * xv;
    }
    float* zp = z + ((size_t)(v - n0) << 8) + (hh << 7) + i;  // [vloc][b][i]
    zp[0] = z0; zp[32] = z1; zp[64] = z2; zp[96] = z3;        // b = 4hh+{0..3}
  }
}

// ---------------- finish GEMM: [cnt,288] @ [288,32] + bias (+relu) ----------
// block = 256 thr = 64 nodes: thread (o = tid&31, g = tid>>5) -> 8 nodes.
// V (9216 floats) + loop staged in LDS; Vl[k*32+o] reads are conflict-free.
__global__ void __launch_bounds__(256) k_finish(const float* __restrict__ z,
                                                const float* __restrict__ xin,
                                                const float* __restrict__ V,    // [8][32][32]
                                                const float* __restrict__ lp,   // [32][32]
                                                const float* __restrict__ bias, // [32]
                                                float* __restrict__ hout,
                                                int n0, int n1, int do_relu) {
  __shared__ float Vl[288 * 32];
  __shared__ float bl[32];
  int tid = threadIdx.x;
  {
    const float4* v4 = reinterpret_cast<const float4*>(V);
    const float4* l4 = reinterpret_cast<const float4*>(lp);
    float4* d4 = reinterpret_cast<float4*>(Vl);
    for (int t = tid; t < 2048; t += 256) d4[t] = v4[t];          // V rows 0..255
    if (tid < 256) d4[2048 + tid] = l4[tid];                      // loop rows 256..287
    if (tid < 32) bl[tid] = bias[tid];
  }
  __syncthreads();
  int o = tid & 31, g = tid >> 5;
  int base = n0 + blockIdx.x * 64 + g * 8;
  float acc[8];
  const float4* zp[8];
  const float4* xp[8];
  int valid[8];
#pragma unroll
  for (int j = 0; j < 8; ++j) {
    int n = base + j;
    valid[j] = (n < n1);
    int nc = valid[j] ? n : n1 - 1;
    zp[j] = reinterpret_cast<const float4*>(z + ((size_t)(nc - n0) << 8));
    xp[j] = reinterpret_cast<const float4*>(xin + ((size_t)nc << 5));
    acc[j] = bl[o];
  }
  for (int k4 = 0; k4 < 64; ++k4) {          // z part: k = 0..255
    int k = k4 << 2;
    float w0 = Vl[(k + 0) * 32 + o], w1 = Vl[(k + 1) * 32 + o],
          w2 = Vl[(k + 2) * 32 + o], w3 = Vl[(k + 3) * 32 + o];
#pragma unroll
    for (int j = 0; j < 8; ++j) {
      float4 zv = zp[j][k4];
      acc[j] += zv.x * w0 + zv.y * w1 + zv.z * w2 + zv.w * w3;
    }
  }
#pragma unroll
  for (int k4 = 0; k4 < 8; ++k4) {           // self-loop part: rows 256..287
    int k = 256 + (k4 << 2);
    float w0 = Vl[(k + 0) * 32 + o], w1 = Vl[(k + 1) * 32 + o],
          w2 = Vl[(k + 2) * 32 + o], w3 = Vl[(k + 3) * 32 + o];
#pragma unroll
    for (int j = 0; j < 8; ++j) {
      float4 xv = xp[j][k4];
      acc[j] += xv.x * w0 + xv.y * w1 + xv.z * w2 + xv.w * w3;
    }
  }
#pragma unroll
  for (int j = 0; j < 8; ++j) {
    if (valid[j]) {
      float vv = do_relu ? fmaxf(acc[j], 0.f) : acc[j];
      hout[((size_t)(base + j) << 5) | o] = vv;   // coalesced 128 B
    }
  }
}

// ---------------- launch ----------------------------------------------------
extern "C" void kernel_launch(void* const* d_in, const int* in_sizes, int n_in,
                              void* d_out, int out_size, void* d_ws, size_t ws_size,
                              hipStream_t stream) {
  const float* x   = (const float*)d_in[0];
  const int* src   = (const int*)d_in[1];
  const int* dst   = (const int*)d_in[2];
  const int* et    = (const int*)d_in[3];
  const float* V1  = (const float*)d_in[4];
  const float* a1  = (const float*)d_in[5];
  const float* lp1 = (const float*)d_in[6];
  const float* b1  = (const float*)d_in[7];
  const float* V2  = (const float*)d_in[8];
  const float* a2  = (const float*)d_in[9];
  const float* lp2 = (const float*)d_in[10];
  const float* b2  = (const float*)d_in[11];
  float* out = (float*)d_out;

  // workspace layout (bytes)
  char* w = (char*)d_ws;
  int*   offs = (int*)(w + 0);                 //   400,000 B (NN ints)
  int*   aux  = (int*)(w + 400128);            //       512 B (98 ints)
  int*   es   = (int*)(w + 400640);            // 6,400,000 -> 6,800,640
  float* h1   = (float*)(w + 6800640);         // 12,800,000 -> 19,600,640
  const size_t Z_OFF = 19600640;
  if (ws_size < Z_OFF + (size_t)4096 * 1024) return;  // need >= 4096-node chunks
  int cap = (int)((ws_size - Z_OFF) / 1024);   // nodes per chunk (256 floats each)
  if (cap > NN) cap = NN;
  float* z = (float*)(w + Z_OFF);
  int nch = (NN + cap - 1) / cap;
  int cs  = (NN + nch - 1) / nch;              // equal-ish chunk size

  hipMemsetAsync(offs, 0, (size_t)NN * 4, stream);

  k_hist<<<(NE + 255) / 256, 256, 0, stream>>>(dst, offs);

  int nScanBlk = (NN + 1023) / 1024;  // 98
  k_scan1<<<nScanBlk, 256, 0, stream>>>(offs, aux, NN);
  k_scan2<<<1, 256, 0, stream>>>(aux, nScanBlk);
  k_scan3<<<(NN + 255) / 256, 256, 0, stream>>>(offs, aux, NN);

  k_scatter<<<(NE + 255) / 256, 256, 0, stream>>>(src, dst, et, offs, es);

  // layer 1: x -> h1 (relu);  layer 2: h1 -> out
  for (int c = 0; c < nch; ++c) {
    int n0 = c * cs, n1 = n0 + cs;
    if (n1 > NN) n1 = NN;
    int cnt = n1 - n0;
    k_edge<<<2048, 256, 0, stream>>>(x, offs, es, a1, z, n0, n1);
    k_finish<<<(cnt + 63) / 64, 256, 0, stream>>>(z, x, V1, lp1, b1, h1, n0, n1, 1);
  }
  for (int c = 0; c < nch; ++c) {
    int n0 = c * cs, n1 = n0 + cs;
    if (n1 > NN) n1 = NN;
    int cnt = n1 - n0;
    k_edge<<<2048, 256, 0, stream>>>(h1, offs, es, a2, z, n0, n1);
    k_finish<<<(cnt + 63) / 64, 256, 0, stream>>>(z, h1, V2, lp2, b2, out, n0, n1, 0);
  }
}

// Round 11
// 473.116 us; speedup vs baseline: 3.9864x; 1.9070x over previous
//
#include <hip/hip_runtime.h>
#include <hip/hip_bf16.h>

// Problem constants (from reference)
#define NN 100000          // nodes
#define NE 1600000         // edges
#define NR 20              // relations
#define NB 8               // bases
#define FD 32              // feature dim (in = hidden = out = 32)

// Basis trick: h[v] = sum_b ( sum_{e->v} a[r_e,b] x[src_e] ) @ V_b  + x[v]@W_loop + bias
//   edge phase:  z[v][b][i] += a[r][b] * x[s][i]   (bf16 z, CSR, no atomics)
//   finish:      MFMA GEMM [cnt,288] @ [288,32], K = 256 (z,bf16) + 32 (x, cvt on fly)
// k index = b*32+i, so Wcat rows 0..255 = V.flat, 256..287 = loop  (no reorder).

typedef short short8 __attribute__((ext_vector_type(8)));
typedef float f32x4  __attribute__((ext_vector_type(4)));

__device__ __forceinline__ unsigned short f2bf(float f) {
  union { float f; unsigned u; } c; c.f = f;
  unsigned r = c.u + 0x7FFF + ((c.u >> 16) & 1);   // RNE
  return (unsigned short)(r >> 16);
}

// ---------------- histogram over dst ----------------------------------------
__global__ void k_hist(const int* __restrict__ dst, int* __restrict__ hist) {
  int e = blockIdx.x * 256 + threadIdx.x;
  if (e < NE) atomicAdd(&hist[dst[e]], 1);
}

// ---------------- hierarchical exclusive scan (1024 elems / block) ----------
__global__ void k_scan1(int* __restrict__ data, int* __restrict__ aux, int n) {
  __shared__ int sd[256];
  int t = threadIdx.x, blk = blockIdx.x;
  int base = blk * 1024 + t * 4;
  int v[4];
#pragma unroll
  for (int j = 0; j < 4; ++j) v[j] = (base + j < n) ? data[base + j] : 0;
  int s = v[0] + v[1] + v[2] + v[3];
  sd[t] = s;
  __syncthreads();
  for (int off = 1; off < 256; off <<= 1) {
    int x = (t >= off) ? sd[t - off] : 0;
    __syncthreads();
    sd[t] += x;
    __syncthreads();
  }
  int run = sd[t] - s;
  if (t == 255) aux[blk] = sd[255];
#pragma unroll
  for (int j = 0; j < 4; ++j) {
    if (base + j < n) { data[base + j] = run; run += v[j]; }
  }
}

__global__ void k_scan2(int* __restrict__ aux, int n) {  // single block
  __shared__ int sd[256];
  int t = threadIdx.x;
  int loc[9];
  int s = 0;
#pragma unroll
  for (int j = 0; j < 9; ++j) {
    int idx = t * 9 + j;
    int v = (idx < n) ? aux[idx] : 0;
    loc[j] = s;
    s += v;
  }
  sd[t] = s;
  __syncthreads();
  for (int off = 1; off < 256; off <<= 1) {
    int x = (t >= off) ? sd[t - off] : 0;
    __syncthreads();
    sd[t] += x;
    __syncthreads();
  }
  int excl = sd[t] - s;
#pragma unroll
  for (int j = 0; j < 9; ++j) {
    int idx = t * 9 + j;
    if (idx < n) aux[idx] = excl + loc[j];
  }
}

__global__ void k_scan3(int* __restrict__ data, const int* __restrict__ aux, int n) {
  int i = blockIdx.x * 256 + threadIdx.x;
  if (i < n) data[i] += aux[i >> 10];
}

// ---------------- scatter edges into dst-sorted order (4 B records) ---------
__global__ void k_scatter(const int* __restrict__ src, const int* __restrict__ dst,
                          const int* __restrict__ et, int* __restrict__ offs,
                          int* __restrict__ es) {
  int e = blockIdx.x * 256 + threadIdx.x;
  if (e >= NE) return;
  int pos = atomicAdd(&offs[dst[e]], 1);
  es[pos] = (src[e] << 5) | et[e];
}
// After scatter: offs[v] = end of row v; start = (v==0) ? 0 : offs[v-1].

// ------- B-fragment precompute: Wcat[288][32] -> per-lane MFMA fragments ----
// Bfrag[ks 0..8][ot 0..1][lane 0..63][j 0..7] bf16, contiguous per lane.
// B layout for mfma_f32_16x16x32_bf16: lane holds B[(lane>>4)*8+j][lane&15].
__global__ void k_bfrag(const float* __restrict__ V1, const float* __restrict__ lp1,
                        const float* __restrict__ V2, const float* __restrict__ lp2,
                        unsigned short* __restrict__ Bf1, unsigned short* __restrict__ Bf2) {
  int t = blockIdx.x * 256 + threadIdx.x;
  if (t >= 2 * 9216) return;
  int layer = t / 9216;
  int idx = t - layer * 9216;
  int kstep = idx >> 10;
  int rem = idx & 1023;
  int otile = rem >> 9;
  int li = (rem >> 3) & 63;
  int j = idx & 7;
  int k = kstep * 32 + ((li >> 4) << 3) + j;
  int o = otile * 16 + (li & 15);
  const float* V = layer ? V2 : V1;
  const float* lp = layer ? lp2 : lp1;
  float val = (k < 256) ? V[k * 32 + o] : lp[(k - 256) * 32 + o];
  (layer ? Bf2 : Bf1)[idx] = f2bf(val);
}

// ---------------- edge phase: wave-per-node CSR aggregation, bf16 z out -----
// lane l: i = l&31, hh = l>>5. Accumulates z[b][i] for b = 4*hh + {0..3}.
// 8-edge batch -> 8 independent x gathers in flight.
__global__ void __launch_bounds__(256) k_edge(const float* __restrict__ xin,
                                              const int* __restrict__ offs,
                                              const int* __restrict__ es,
                                              const float* __restrict__ arel,  // [20][8]
                                              unsigned short* __restrict__ zb, // [cap][256] bf16
                                              int n0, int n1) {
  int wid = (blockIdx.x * 256 + threadIdx.x) >> 6;
  int nw  = (gridDim.x * 256) >> 6;
  int l = threadIdx.x & 63;
  int i = l & 31, hh = l >> 5;
  const float4* aT = reinterpret_cast<const float4*>(arel);
  for (int v = n0 + wid; v < n1; v += nw) {
    int e0 = (v == 0) ? 0 : offs[v - 1];
    int e1 = offs[v];
    e0 = __builtin_amdgcn_readfirstlane(e0);
    e1 = __builtin_amdgcn_readfirstlane(e1);
    float z0 = 0.f, z1 = 0.f, z2 = 0.f, z3 = 0.f;
    int e = e0;
    for (; e + 8 <= e1; e += 8) {
      int r0 = es[e],     r1 = es[e + 1], r2 = es[e + 2], r3 = es[e + 3];
      int r4 = es[e + 4], r5 = es[e + 5], r6 = es[e + 6], r7 = es[e + 7];
      float x0 = xin[((r0 >> 5) << 5) | i];
      float x1 = xin[((r1 >> 5) << 5) | i];
      float x2 = xin[((r2 >> 5) << 5) | i];
      float x3 = xin[((r3 >> 5) << 5) | i];
      float x4 = xin[((r4 >> 5) << 5) | i];
      float x5 = xin[((r5 >> 5) << 5) | i];
      float x6 = xin[((r6 >> 5) << 5) | i];
      float x7 = xin[((r7 >> 5) << 5) | i];
      float4 a0 = aT[((r0 & 31) << 1) | hh];
      float4 a1 = aT[((r1 & 31) << 1) | hh];
      float4 a2 = aT[((r2 & 31) << 1) | hh];
      float4 a3 = aT[((r3 & 31) << 1) | hh];
      float4 a4 = aT[((r4 & 31) << 1) | hh];
      float4 a5 = aT[((r5 & 31) << 1) | hh];
      float4 a6 = aT[((r6 & 31) << 1) | hh];
      float4 a7 = aT[((r7 & 31) << 1) | hh];
      z0 += a0.x * x0; z1 += a0.y * x0; z2 += a0.z * x0; z3 += a0.w * x0;
      z0 += a1.x * x1; z1 += a1.y * x1; z2 += a1.z * x1; z3 += a1.w * x1;
      z0 += a2.x * x2; z1 += a2.y * x2; z2 += a2.z * x2; z3 += a2.w * x2;
      z0 += a3.x * x3; z1 += a3.y * x3; z2 += a3.z * x3; z3 += a3.w * x3;
      z0 += a4.x * x4; z1 += a4.y * x4; z2 += a4.z * x4; z3 += a4.w * x4;
      z0 += a5.x * x5; z1 += a5.y * x5; z2 += a5.z * x5; z3 += a5.w * x5;
      z0 += a6.x * x6; z1 += a6.y * x6; z2 += a6.z * x6; z3 += a6.w * x6;
      z0 += a7.x * x7; z1 += a7.y * x7; z2 += a7.z * x7; z3 += a7.w * x7;
    }
    for (; e + 4 <= e1; e += 4) {
      int r0 = es[e], r1 = es[e + 1], r2 = es[e + 2], r3 = es[e + 3];
      float x0 = xin[((r0 >> 5) << 5) | i];
      float x1 = xin[((r1 >> 5) << 5) | i];
      float x2 = xin[((r2 >> 5) << 5) | i];
      float x3 = xin[((r3 >> 5) << 5) | i];
      float4 a0 = aT[((r0 & 31) << 1) | hh];
      float4 a1 = aT[((r1 & 31) << 1) | hh];
      float4 a2 = aT[((r2 & 31) << 1) | hh];
      float4 a3 = aT[((r3 & 31) << 1) | hh];
      z0 += a0.x * x0; z1 += a0.y * x0; z2 += a0.z * x0; z3 += a0.w * x0;
      z0 += a1.x * x1; z1 += a1.y * x1; z2 += a1.z * x1; z3 += a1.w * x1;
      z0 += a2.x * x2; z1 += a2.y * x2; z2 += a2.z * x2; z3 += a2.w * x2;
      z0 += a3.x * x3; z1 += a3.y * x3; z2 += a3.z * x3; z3 += a3.w * x3;
    }
    for (; e < e1; ++e) {
      int rec = es[e];
      int s = rec >> 5, r = rec & 31;
      float xv = xin[(s << 5) | i];
      float4 av = aT[(r << 1) | hh];
      z0 += av.x * xv; z1 += av.y * xv; z2 += av.z * xv; z3 += av.w * xv;
    }
    // z layout: k = b*32+i = hh*128 + q*32 + i  (b = 4hh+q)
    unsigned short* zp = zb + ((size_t)(v - n0) << 8) + (hh << 7) + i;
    zp[0]  = f2bf(z0);
    zp[32] = f2bf(z1);
    zp[64] = f2bf(z2);
    zp[96] = f2bf(z3);
  }
}

// ---------------- finish: MFMA GEMM [cnt,288]@[288,32] + bias (+relu) -------
// Wave per 16-node tile (grid-stride). B fragments in VGPRs for whole kernel.
// A: lane holds A[lane&15][(lane>>4)*8 + j]; C/D: col=lane&15, row=(lane>>4)*4+reg.
__global__ void __launch_bounds__(256) k_finish(const unsigned short* __restrict__ zb,
                                                const float* __restrict__ xin,
                                                const unsigned short* __restrict__ Bfrag,
                                                const float* __restrict__ bias,
                                                float* __restrict__ hout,
                                                int n0, int n1, int do_relu) {
  int lane = threadIdx.x & 63;
  int wid = (blockIdx.x * 256 + threadIdx.x) >> 6;
  int nwv = (gridDim.x * 256) >> 6;
  const short8* Bp = reinterpret_cast<const short8*>(Bfrag);
  short8 bf[9][2];
#pragma unroll
  for (int ks = 0; ks < 9; ++ks)
#pragma unroll
    for (int ot = 0; ot < 2; ++ot)
      bf[ks][ot] = Bp[((ks * 2 + ot) << 6) + lane];
  float bsv0 = bias[lane & 15];
  float bsv1 = bias[16 + (lane & 15)];
  int cnt = n1 - n0;
  int tiles = (cnt + 15) >> 4;
  int row = lane & 15;
  int kg = lane >> 4;           // k-group 0..3
  for (int t = wid; t < tiles; t += nwv) {
    int nb = t << 4;
    int r = nb + row;
    int rc = (r < cnt) ? r : (cnt - 1);
    const short8* zrow = reinterpret_cast<const short8*>(zb + ((size_t)rc << 8));
    f32x4 acc0 = {0.f, 0.f, 0.f, 0.f};
    f32x4 acc1 = {0.f, 0.f, 0.f, 0.f};
#pragma unroll
    for (int ks = 0; ks < 8; ++ks) {
      short8 af = zrow[(ks << 2) + kg];
      acc0 = __builtin_amdgcn_mfma_f32_16x16x32_bf16(af, bf[ks][0], acc0, 0, 0, 0);
      acc1 = __builtin_amdgcn_mfma_f32_16x16x32_bf16(af, bf[ks][1], acc1, 0, 0, 0);
    }
    {  // self-loop K-step: x fp32 -> bf16 on the fly
      const float4* xr = reinterpret_cast<const float4*>(xin + ((size_t)(n0 + rc) << 5) + (kg << 3));
      float4 xa = xr[0], xb2 = xr[1];
      short8 xs;
      xs[0] = (short)f2bf(xa.x);  xs[1] = (short)f2bf(xa.y);
      xs[2] = (short)f2bf(xa.z);  xs[3] = (short)f2bf(xa.w);
      xs[4] = (short)f2bf(xb2.x); xs[5] = (short)f2bf(xb2.y);
      xs[6] = (short)f2bf(xb2.z); xs[7] = (short)f2bf(xb2.w);
      acc0 = __builtin_amdgcn_mfma_f32_16x16x32_bf16(xs, bf[8][0], acc0, 0, 0, 0);
      acc1 = __builtin_amdgcn_mfma_f32_16x16x32_bf16(xs, bf[8][1], acc1, 0, 0, 0);
    }
#pragma unroll
    for (int q = 0; q < 4; ++q) {
      int orow = (kg << 2) + q;
      int n = nb + orow;
      if (n < cnt) {
        float v0 = acc0[q] + bsv0;
        float v1 = acc1[q] + bsv1;
        if (do_relu) { v0 = fmaxf(v0, 0.f); v1 = fmaxf(v1, 0.f); }
        float* hp = hout + ((size_t)(n0 + n) << 5);
        hp[row] = v0;
        hp[16 + row] = v1;
      }
    }
  }
}

// ---------------- launch ----------------------------------------------------
extern "C" void kernel_launch(void* const* d_in, const int* in_sizes, int n_in,
                              void* d_out, int out_size, void* d_ws, size_t ws_size,
                              hipStream_t stream) {
  const float* x   = (const float*)d_in[0];
  const int* src   = (const int*)d_in[1];
  const int* dst   = (const int*)d_in[2];
  const int* et    = (const int*)d_in[3];
  const float* V1  = (const float*)d_in[4];
  const float* a1  = (const float*)d_in[5];
  const float* lp1 = (const float*)d_in[6];
  const float* b1  = (const float*)d_in[7];
  const float* V2  = (const float*)d_in[8];
  const float* a2  = (const float*)d_in[9];
  const float* lp2 = (const float*)d_in[10];
  const float* b2  = (const float*)d_in[11];
  float* out = (float*)d_out;

  // workspace layout (bytes)
  char* w = (char*)d_ws;
  int* offs = (int*)(w + 0);                    //   400,000 -> pad 400,128
  int* aux  = (int*)(w + 400128);               //       392 -> pad 400,640
  int* es   = (int*)(w + 400640);               // 6,400,000 -> 6,800,640
  float* h1 = (float*)(w + 6800640);            // 12,800,000 -> 19,600,640
  unsigned short* Bf1 = (unsigned short*)(w + 19600640);  // 18,432 -> 19,619,072
  unsigned short* Bf2 = (unsigned short*)(w + 19619072);  // 18,432 -> 19,637,504
  const size_t ZB_OFF = 19637504;
  if (ws_size < ZB_OFF + (size_t)4096 * 512) return;   // need >= 4096-node chunks
  unsigned short* zb = (unsigned short*)(w + ZB_OFF);
  int cap = (int)((ws_size - ZB_OFF) / 512);    // nodes per chunk (256 bf16 each)
  if (cap > NN) cap = NN;
  int nch = (NN + cap - 1) / cap;
  int cs  = (((NN + nch - 1) / nch) + 15) & ~15;  // chunk size, multiple of 16

  hipMemsetAsync(offs, 0, (size_t)NN * 4, stream);

  k_hist<<<(NE + 255) / 256, 256, 0, stream>>>(dst, offs);

  int nScanBlk = (NN + 1023) / 1024;  // 98
  k_scan1<<<nScanBlk, 256, 0, stream>>>(offs, aux, NN);
  k_scan2<<<1, 256, 0, stream>>>(aux, nScanBlk);
  k_scan3<<<(NN + 255) / 256, 256, 0, stream>>>(offs, aux, NN);

  k_scatter<<<(NE + 255) / 256, 256, 0, stream>>>(src, dst, et, offs, es);

  k_bfrag<<<(2 * 9216 + 255) / 256, 256, 0, stream>>>(V1, lp1, V2, lp2, Bf1, Bf2);

  // layer 1: x -> h1 (relu);  layer 2: h1 -> out
  for (int c = 0; c < nch; ++c) {
    int n0 = c * cs, n1 = n0 + cs;
    if (n1 > NN) n1 = NN;
    if (n0 >= n1) break;
    int tiles = ((n1 - n0) + 15) >> 4;
    int fblk = (tiles + 3) / 4; if (fblk > 512) fblk = 512;
    k_edge<<<2048, 256, 0, stream>>>(x, offs, es, a1, zb, n0, n1);
    k_finish<<<fblk, 256, 0, stream>>>(zb, x, Bf1, b1, h1, n0, n1, 1);
  }
  for (int c = 0; c < nch; ++c) {
    int n0 = c * cs, n1 = n0 + cs;
    if (n1 > NN) n1 = NN;
    if (n0 >= n1) break;
    int tiles = ((n1 - n0) + 15) >> 4;
    int fblk = (tiles + 3) / 4; if (fblk > 512) fblk = 512;
    k_edge<<<2048, 256, 0, stream>>>(h1, offs, es, a2, zb, n0, n1);
    k_finish<<<fblk, 256, 0, stream>>>(zb, h1, Bf2, b2, out, n0, n1, 0);
  }
}

// Round 12
// 423.431 us; speedup vs baseline: 4.4542x; 1.1173x over previous
//
#include <hip/hip_runtime.h>
#include <hip/hip_bf16.h>

// Problem constants (from reference)
#define NN 100000          // nodes
#define NE 1600000         // edges
#define NR 20              // relations
#define NB 8               // bases
#define FD 32              // feature dim (in = hidden = out = 32)

#define EPB 8192                       // edges per bin block
#define NBB ((NE + EPB - 1) / EPB)     // 196 bin blocks
#define NBKT ((NN + 255) / 256)        // 391 buckets (256 nodes each)

typedef short short8 __attribute__((ext_vector_type(8)));
typedef float f32x4  __attribute__((ext_vector_type(4)));

__device__ __forceinline__ unsigned short f2bf(float f) {
  union { float f; unsigned u; } c; c.f = f;
  unsigned r = c.u + 0x7FFF + ((c.u >> 16) & 1);   // RNE
  return (unsigned short)(r >> 16);
}
__device__ __forceinline__ float bf2f(unsigned short u) {
  union { unsigned u; float f; } c; c.u = ((unsigned)u) << 16; return c.f;
}

// ---------------- histogram over dst (counts into ioffs) --------------------
__global__ void k_hist(const int* __restrict__ dst, int* __restrict__ hist) {
  int e = blockIdx.x * 256 + threadIdx.x;
  if (e < NE) atomicAdd(&hist[dst[e]], 1);
}

// ---------------- hierarchical exclusive scan (1024 elems / block) ----------
__global__ void k_scan1(int* __restrict__ data, int* __restrict__ aux, int n) {
  __shared__ int sd[256];
  int t = threadIdx.x, blk = blockIdx.x;
  int base = blk * 1024 + t * 4;
  int v[4];
#pragma unroll
  for (int j = 0; j < 4; ++j) v[j] = (base + j < n) ? data[base + j] : 0;
  int s = v[0] + v[1] + v[2] + v[3];
  sd[t] = s;
  __syncthreads();
  for (int off = 1; off < 256; off <<= 1) {
    int x = (t >= off) ? sd[t - off] : 0;
    __syncthreads();
    sd[t] += x;
    __syncthreads();
  }
  int run = sd[t] - s;
  if (t == 255) aux[blk] = sd[255];
#pragma unroll
  for (int j = 0; j < 4; ++j) {
    if (base + j < n) { data[base + j] = run; run += v[j]; }
  }
}

__global__ void k_scan2(int* __restrict__ aux, int n) {  // single block
  __shared__ int sd[256];
  int t = threadIdx.x;
  int loc[9];
  int s = 0;
#pragma unroll
  for (int j = 0; j < 9; ++j) {
    int idx = t * 9 + j;
    int v = (idx < n) ? aux[idx] : 0;
    loc[j] = s;
    s += v;
  }
  sd[t] = s;
  __syncthreads();
  for (int off = 1; off < 256; off <<= 1) {
    int x = (t >= off) ? sd[t - off] : 0;
    __syncthreads();
    sd[t] += x;
    __syncthreads();
  }
  int excl = sd[t] - s;
#pragma unroll
  for (int j = 0; j < 9; ++j) {
    int idx = t * 9 + j;
    if (idx < n) aux[idx] = excl + loc[j];
  }
}

__global__ void k_scan3(int* __restrict__ data, const int* __restrict__ aux, int n) {
  int i = blockIdx.x * 256 + threadIdx.x;
  if (i < n) data[i] += aux[i >> 10];
}

__global__ void k_endcap(int* __restrict__ ioffs) {
  if (threadIdx.x == 0 && blockIdx.x == 0) ioffs[NN] = NE;
}

// ------- bin pass: block-local bucket sort into block-major regions ---------
// Block g bins its EPB-edge chunk by bucket (dst>>8) into binbuf[g*EPB ...).
// Writes are dense within the block's 32 KB region -> full-line writebacks.
// rec pack: src(17b)<<13 | (dst&255)<<5 | rel(5b)
__global__ void __launch_bounds__(256) k_bin(const int* __restrict__ src,
                                             const int* __restrict__ dst,
                                             const int* __restrict__ et,
                                             int* __restrict__ binbuf,
                                             int* __restrict__ bcnt,
                                             int* __restrict__ segoff) {
  __shared__ int sA[512], sB[512];
  int g = blockIdx.x, t = threadIdx.x;
  int e0 = g * EPB;
  int e1 = e0 + EPB; if (e1 > NE) e1 = NE;
  sA[t] = 0; sA[t + 256] = 0;
  __syncthreads();
  for (int e = e0 + t; e < e1; e += 256) atomicAdd(&sA[dst[e] >> 8], 1);
  __syncthreads();
  for (int b = t; b < NBKT; b += 256) bcnt[g * NBKT + b] = sA[b];
  // inclusive Hillis-Steele scan over 512 (ping-pong)
  int* pa = sA; int* pb = sB;
  for (int off = 1; off < 512; off <<= 1) {
    __syncthreads();
    for (int idx = t; idx < 512; idx += 256) {
      int v = pa[idx];
      if (idx >= off) v += pa[idx - off];
      pb[idx] = v;
    }
    int* tmp = pa; pa = pb; pb = tmp;
  }
  __syncthreads();
  // exclusive prefix -> segment offsets + LDS cursors (in pb)
  for (int b = t; b < NBKT; b += 256) {
    int ex = b ? pa[b - 1] : 0;
    segoff[g * NBKT + b] = e0 + ex;
    pb[b] = ex;
  }
  __syncthreads();
  for (int e = e0 + t; e < e1; e += 256) {
    int d = dst[e];
    int pos = atomicAdd(&pb[d >> 8], 1);
    binbuf[e0 + pos] = (src[e] << 13) | ((d & 255) << 5) | et[e];
  }
}

// ------- bucket pass: block per bucket, scatter to final CSR positions ------
// Writes land dense in the bucket's contiguous es window (~16 KB, L2-resident).
__global__ void __launch_bounds__(256) k_bsort(const int* __restrict__ binbuf,
                                               const int* __restrict__ bcnt,
                                               const int* __restrict__ segoff,
                                               const int* __restrict__ ioffs,
                                               int* __restrict__ es) {
  __shared__ int cur[256];
  __shared__ int scnt[NBB], ssof[NBB];
  int b = blockIdx.x, t = threadIdx.x;
  int node = b * 256 + t;
  cur[t] = (node < NN) ? ioffs[node] : 0;
  for (int g = t; g < NBB; g += 256) {
    scnt[g] = bcnt[g * NBKT + b];
    ssof[g] = segoff[g * NBKT + b];
  }
  __syncthreads();
  int w = t >> 6, l = t & 63;
  for (int g = w; g < NBB; g += 4) {
    int c = scnt[g], so = ssof[g];
    for (int base = l; base < c; base += 64) {
      int v = binbuf[so + base];
      int j = (v >> 5) & 255;
      int pos = atomicAdd(&cur[j], 1);
      es[pos] = ((v >> 13) << 5) | (v & 31);
    }
  }
}

// ---------------- x -> bf16 cast (NN*FD = 3.2M elems, exact /8) -------------
__global__ void k_xcast(const float* __restrict__ x, unsigned short* __restrict__ xb) {
  int t = blockIdx.x * 256 + threadIdx.x;
  if (t >= (NN * FD) / 8) return;
  const float4* xp = reinterpret_cast<const float4*>(x) + t * 2;
  float4 a = xp[0], b = xp[1];
  short8 v;
  v[0] = (short)f2bf(a.x); v[1] = (short)f2bf(a.y);
  v[2] = (short)f2bf(a.z); v[3] = (short)f2bf(a.w);
  v[4] = (short)f2bf(b.x); v[5] = (short)f2bf(b.y);
  v[6] = (short)f2bf(b.z); v[7] = (short)f2bf(b.w);
  reinterpret_cast<short8*>(xb)[t] = v;
}

// ------- B-fragment precompute: Wcat[288][32] -> per-lane MFMA fragments ----
__global__ void k_bfrag(const float* __restrict__ V1, const float* __restrict__ lp1,
                        const float* __restrict__ V2, const float* __restrict__ lp2,
                        unsigned short* __restrict__ Bf1, unsigned short* __restrict__ Bf2) {
  int t = blockIdx.x * 256 + threadIdx.x;
  if (t >= 2 * 9216) return;
  int layer = t / 9216;
  int idx = t - layer * 9216;
  int kstep = idx >> 10;
  int rem = idx & 1023;
  int otile = rem >> 9;
  int li = (rem >> 3) & 63;
  int j = idx & 7;
  int k = kstep * 32 + ((li >> 4) << 3) + j;
  int o = otile * 16 + (li & 15);
  const float* V = layer ? V2 : V1;
  const float* lp = layer ? lp2 : lp1;
  float val = (k < 256) ? V[k * 32 + o] : lp[(k - 256) * 32 + o];
  (layer ? Bf2 : Bf1)[idx] = f2bf(val);
}

// ---------------- edge phase: wave-per-node CSR aggregation, bf16 in/out ----
__global__ void __launch_bounds__(256) k_edge(const unsigned short* __restrict__ xin,
                                              const int* __restrict__ ioffs,
                                              const int* __restrict__ es,
                                              const float* __restrict__ arel,  // [20][8]
                                              unsigned short* __restrict__ zb, // [cap][256] bf16
                                              int n0, int n1) {
  int wid = (blockIdx.x * 256 + threadIdx.x) >> 6;
  int nw  = (gridDim.x * 256) >> 6;
  int l = threadIdx.x & 63;
  int i = l & 31, hh = l >> 5;
  const float4* aT = reinterpret_cast<const float4*>(arel);
  for (int v = n0 + wid; v < n1; v += nw) {
    int e0 = __builtin_amdgcn_readfirstlane(ioffs[v]);
    int e1 = __builtin_amdgcn_readfirstlane(ioffs[v + 1]);
    float z0 = 0.f, z1 = 0.f, z2 = 0.f, z3 = 0.f;
    int e = e0;
    for (; e + 8 <= e1; e += 8) {
      int r0 = es[e],     r1 = es[e + 1], r2 = es[e + 2], r3 = es[e + 3];
      int r4 = es[e + 4], r5 = es[e + 5], r6 = es[e + 6], r7 = es[e + 7];
      float x0 = bf2f(xin[((r0 >> 5) << 5) | i]);
      float x1 = bf2f(xin[((r1 >> 5) << 5) | i]);
      float x2 = bf2f(xin[((r2 >> 5) << 5) | i]);
      float x3 = bf2f(xin[((r3 >> 5) << 5) | i]);
      float x4 = bf2f(xin[((r4 >> 5) << 5) | i]);
      float x5 = bf2f(xin[((r5 >> 5) << 5) | i]);
      float x6 = bf2f(xin[((r6 >> 5) << 5) | i]);
      float x7 = bf2f(xin[((r7 >> 5) << 5) | i]);
      float4 a0 = aT[((r0 & 31) << 1) | hh];
      float4 a1 = aT[((r1 & 31) << 1) | hh];
      float4 a2 = aT[((r2 & 31) << 1) | hh];
      float4 a3 = aT[((r3 & 31) << 1) | hh];
      float4 a4 = aT[((r4 & 31) << 1) | hh];
      float4 a5 = aT[((r5 & 31) << 1) | hh];
      float4 a6 = aT[((r6 & 31) << 1) | hh];
      float4 a7 = aT[((r7 & 31) << 1) | hh];
      z0 += a0.x * x0; z1 += a0.y * x0; z2 += a0.z * x0; z3 += a0.w * x0;
      z0 += a1.x * x1; z1 += a1.y * x1; z2 += a1.z * x1; z3 += a1.w * x1;
      z0 += a2.x * x2; z1 += a2.y * x2; z2 += a2.z * x2; z3 += a2.w * x2;
      z0 += a3.x * x3; z1 += a3.y * x3; z2 += a3.z * x3; z3 += a3.w * x3;
      z0 += a4.x * x4; z1 += a4.y * x4; z2 += a4.z * x4; z3 += a4.w * x4;
      z0 += a5.x * x5; z1 += a5.y * x5; z2 += a5.z * x5; z3 += a5.w * x5;
      z0 += a6.x * x6; z1 += a6.y * x6; z2 += a6.z * x6; z3 += a6.w * x6;
      z0 += a7.x * x7; z1 += a7.y * x7; z2 += a7.z * x7; z3 += a7.w * x7;
    }
    for (; e + 4 <= e1; e += 4) {
      int r0 = es[e], r1 = es[e + 1], r2 = es[e + 2], r3 = es[e + 3];
      float x0 = bf2f(xin[((r0 >> 5) << 5) | i]);
      float x1 = bf2f(xin[((r1 >> 5) << 5) | i]);
      float x2 = bf2f(xin[((r2 >> 5) << 5) | i]);
      float x3 = bf2f(xin[((r3 >> 5) << 5) | i]);
      float4 a0 = aT[((r0 & 31) << 1) | hh];
      float4 a1 = aT[((r1 & 31) << 1) | hh];
      float4 a2 = aT[((r2 & 31) << 1) | hh];
      float4 a3 = aT[((r3 & 31) << 1) | hh];
      z0 += a0.x * x0; z1 += a0.y * x0; z2 += a0.z * x0; z3 += a0.w * x0;
      z0 += a1.x * x1; z1 += a1.y * x1; z2 += a1.z * x1; z3 += a1.w * x1;
      z0 += a2.x * x2; z1 += a2.y * x2; z2 += a2.z * x2; z3 += a2.w * x2;
      z0 += a3.x * x3; z1 += a3.y * x3; z2 += a3.z * x3; z3 += a3.w * x3;
    }
    for (; e < e1; ++e) {
      int rec = es[e];
      float xv = bf2f(xin[((rec >> 5) << 5) | i]);
      float4 av = aT[((rec & 31) << 1) | hh];
      z0 += av.x * xv; z1 += av.y * xv; z2 += av.z * xv; z3 += av.w * xv;
    }
    unsigned short* zp = zb + ((size_t)(v - n0) << 8) + (hh << 7) + i;
    zp[0]  = f2bf(z0);
    zp[32] = f2bf(z1);
    zp[64] = f2bf(z2);
    zp[96] = f2bf(z3);
  }
}

// ---------------- finish: MFMA GEMM [cnt,288]@[288,32] + bias (+relu) -------
// Wave per 16-node tile (grid-stride). B fragments in VGPRs for whole kernel.
// Self-loop A-fragment read directly from bf16 xin (already fragment layout).
__global__ void __launch_bounds__(256) k_finish(const unsigned short* __restrict__ zb,
                                                const unsigned short* __restrict__ xin, // bf16 [NN][32]
                                                const unsigned short* __restrict__ Bfrag,
                                                const float* __restrict__ bias,
                                                float* __restrict__ out_f32,       // may be null
                                                unsigned short* __restrict__ out_bf16, // may be null
                                                int n0, int n1, int do_relu) {
  int lane = threadIdx.x & 63;
  int wid = (blockIdx.x * 256 + threadIdx.x) >> 6;
  int nwv = (gridDim.x * 256) >> 6;
  const short8* Bp = reinterpret_cast<const short8*>(Bfrag);
  short8 bf[9][2];
#pragma unroll
  for (int ks = 0; ks < 9; ++ks)
#pragma unroll
    for (int ot = 0; ot < 2; ++ot)
      bf[ks][ot] = Bp[((ks * 2 + ot) << 6) + lane];
  float bsv0 = bias[lane & 15];
  float bsv1 = bias[16 + (lane & 15)];
  int cnt = n1 - n0;
  int tiles = (cnt + 15) >> 4;
  int row = lane & 15;
  int kg = lane >> 4;           // k-group 0..3
  for (int t = wid; t < tiles; t += nwv) {
    int nb = t << 4;
    int r = nb + row;
    int rc = (r < cnt) ? r : (cnt - 1);
    const short8* zrow = reinterpret_cast<const short8*>(zb + ((size_t)rc << 8));
    f32x4 acc0 = {0.f, 0.f, 0.f, 0.f};
    f32x4 acc1 = {0.f, 0.f, 0.f, 0.f};
#pragma unroll
    for (int ks = 0; ks < 8; ++ks) {
      short8 af = zrow[(ks << 2) + kg];
      acc0 = __builtin_amdgcn_mfma_f32_16x16x32_bf16(af, bf[ks][0], acc0, 0, 0, 0);
      acc1 = __builtin_amdgcn_mfma_f32_16x16x32_bf16(af, bf[ks][1], acc1, 0, 0, 0);
    }
    {  // self-loop K-step: bf16 x row IS the A-fragment
      short8 xs = *reinterpret_cast<const short8*>(xin + ((size_t)(n0 + rc) << 5) + (kg << 3));
      acc0 = __builtin_amdgcn_mfma_f32_16x16x32_bf16(xs, bf[8][0], acc0, 0, 0, 0);
      acc1 = __builtin_amdgcn_mfma_f32_16x16x32_bf16(xs, bf[8][1], acc1, 0, 0, 0);
    }
#pragma unroll
    for (int q = 0; q < 4; ++q) {
      int orow = (kg << 2) + q;
      int n = nb + orow;
      if (n < cnt) {
        float v0 = acc0[q] + bsv0;
        float v1 = acc1[q] + bsv1;
        if (do_relu) { v0 = fmaxf(v0, 0.f); v1 = fmaxf(v1, 0.f); }
        size_t base = ((size_t)(n0 + n) << 5);
        if (out_f32) { out_f32[base + row] = v0; out_f32[base + 16 + row] = v1; }
        if (out_bf16) { out_bf16[base + row] = f2bf(v0); out_bf16[base + 16 + row] = f2bf(v1); }
      }
    }
  }
}

// ---------------- launch ----------------------------------------------------
extern "C" void kernel_launch(void* const* d_in, const int* in_sizes, int n_in,
                              void* d_out, int out_size, void* d_ws, size_t ws_size,
                              hipStream_t stream) {
  const float* x   = (const float*)d_in[0];
  const int* src   = (const int*)d_in[1];
  const int* dst   = (const int*)d_in[2];
  const int* et    = (const int*)d_in[3];
  const float* V1  = (const float*)d_in[4];
  const float* a1  = (const float*)d_in[5];
  const float* lp1 = (const float*)d_in[6];
  const float* b1  = (const float*)d_in[7];
  const float* V2  = (const float*)d_in[8];
  const float* a2  = (const float*)d_in[9];
  const float* lp2 = (const float*)d_in[10];
  const float* b2  = (const float*)d_in[11];
  float* out = (float*)d_out;

  // workspace layout (bytes)
  char* w = (char*)d_ws;
  int* ioffs = (int*)(w + 0);                       // 400,004 -> pad 400,128
  int* aux   = (int*)(w + 400128);                  //     392 -> pad 400,640
  int* es    = (int*)(w + 400640);                  // 6,400,000 -> 6,800,640
  int* binbuf= (int*)(w + 6800640);                 // 6,422,528 -> 13,223,168
  int* bcnt  = (int*)(w + 13223168);                // 306,544 -> pad 13,529,728
  int* segoff= (int*)(w + 13529728);                // 306,544 -> pad 13,836,288
  unsigned short* xb  = (unsigned short*)(w + 13836288); // 6,400,000 -> 20,236,288
  unsigned short* h1b = (unsigned short*)(w + 20236288); // 6,400,000 -> 26,636,288
  unsigned short* Bf1 = (unsigned short*)(w + 26636288); // 18,432 -> 26,654,720
  unsigned short* Bf2 = (unsigned short*)(w + 26654720); // 18,432 -> 26,673,152
  const size_t ZB_OFF = 26673152;
  if (ws_size < ZB_OFF + (size_t)4096 * 512) return;
  unsigned short* zb = (unsigned short*)(w + ZB_OFF);
  int cap = (int)((ws_size - ZB_OFF) / 512);
  if (cap > NN) cap = NN;
  int nch = (NN + cap - 1) / cap;
  int cs  = (((NN + nch - 1) / nch) + 15) & ~15;

  hipMemsetAsync(ioffs, 0, (size_t)NN * 4, stream);

  k_hist<<<(NE + 255) / 256, 256, 0, stream>>>(dst, ioffs);

  int nScanBlk = (NN + 1023) / 1024;  // 98
  k_scan1<<<nScanBlk, 256, 0, stream>>>(ioffs, aux, NN);
  k_scan2<<<1, 256, 0, stream>>>(aux, nScanBlk);
  k_scan3<<<(NN + 255) / 256, 256, 0, stream>>>(ioffs, aux, NN);
  k_endcap<<<1, 64, 0, stream>>>(ioffs);

  k_bin<<<NBB, 256, 0, stream>>>(src, dst, et, binbuf, bcnt, segoff);
  k_bsort<<<NBKT, 256, 0, stream>>>(binbuf, bcnt, segoff, ioffs, es);

  k_xcast<<<((NN * FD / 8) + 255) / 256, 256, 0, stream>>>(x, xb);
  k_bfrag<<<(2 * 9216 + 255) / 256, 256, 0, stream>>>(V1, lp1, V2, lp2, Bf1, Bf2);

  // layer 1: xb -> h1b (bf16, relu);  layer 2: h1b -> out (fp32)
  for (int c = 0; c < nch; ++c) {
    int n0 = c * cs, n1 = n0 + cs;
    if (n1 > NN) n1 = NN;
    if (n0 >= n1) break;
    int tiles = ((n1 - n0) + 15) >> 4;
    int fblk = (tiles + 3) / 4; if (fblk > 512) fblk = 512;
    k_edge<<<2048, 256, 0, stream>>>(xb, ioffs, es, a1, zb, n0, n1);
    k_finish<<<fblk, 256, 0, stream>>>(zb, xb, Bf1, b1, nullptr, h1b, n0, n1, 1);
  }
  for (int c = 0; c < nch; ++c) {
    int n0 = c * cs, n1 = n0 + cs;
    if (n1 > NN) n1 = NN;
    if (n0 >= n1) break;
    int tiles = ((n1 - n0) + 15) >> 4;
    int fblk = (tiles + 3) / 4; if (fblk > 512) fblk = 512;
    k_edge<<<2048, 256, 0, stream>>>(h1b, ioffs, es, a2, zb, n0, n1);
    k_finish<<<fblk, 256, 0, stream>>>(zb, h1b, Bf2, b2, out, nullptr, n0, n1, 0);
  }
}

// Round 13
// 398.079 us; speedup vs baseline: 4.7379x; 1.0637x over previous
//
#include <hip/hip_runtime.h>
#include <hip/hip_bf16.h>

// Problem constants (from reference)
#define NN 100000          // nodes
#define NE 1600000         // edges
#define NR 20              // relations
#define NB 8               // bases
#define FD 32              // feature dim (in = hidden = out = 32)

#define EPB 8192                       // edges per bin block
#define NBB ((NE + EPB - 1) / EPB)     // 196 bin blocks
#define NBKT ((NN + 255) / 256)        // 391 buckets (256 nodes each)

typedef short short8 __attribute__((ext_vector_type(8)));
typedef float f32x4  __attribute__((ext_vector_type(4)));

__device__ __forceinline__ unsigned short f2bf(float f) {
  union { float f; unsigned u; } c; c.f = f;
  unsigned r = c.u + 0x7FFF + ((c.u >> 16) & 1);   // RNE
  return (unsigned short)(r >> 16);
}
__device__ __forceinline__ float bf2f(unsigned short u) {
  union { unsigned u; float f; } c; c.u = ((unsigned)u) << 16; return c.f;
}

// ---------------- histogram over dst (counts into ioffs) --------------------
__global__ void k_hist(const int* __restrict__ dst, int* __restrict__ hist) {
  int e = blockIdx.x * 256 + threadIdx.x;
  if (e < NE) atomicAdd(&hist[dst[e]], 1);
}

// ---------------- hierarchical exclusive scan (1024 elems / block) ----------
__global__ void k_scan1(int* __restrict__ data, int* __restrict__ aux, int n) {
  __shared__ int sd[256];
  int t = threadIdx.x, blk = blockIdx.x;
  int base = blk * 1024 + t * 4;
  int v[4];
#pragma unroll
  for (int j = 0; j < 4; ++j) v[j] = (base + j < n) ? data[base + j] : 0;
  int s = v[0] + v[1] + v[2] + v[3];
  sd[t] = s;
  __syncthreads();
  for (int off = 1; off < 256; off <<= 1) {
    int x = (t >= off) ? sd[t - off] : 0;
    __syncthreads();
    sd[t] += x;
    __syncthreads();
  }
  int run = sd[t] - s;
  if (t == 255) aux[blk] = sd[255];
#pragma unroll
  for (int j = 0; j < 4; ++j) {
    if (base + j < n) { data[base + j] = run; run += v[j]; }
  }
}

__global__ void k_scan2(int* __restrict__ aux, int n) {  // single block
  __shared__ int sd[256];
  int t = threadIdx.x;
  int loc[9];
  int s = 0;
#pragma unroll
  for (int j = 0; j < 9; ++j) {
    int idx = t * 9 + j;
    int v = (idx < n) ? aux[idx] : 0;
    loc[j] = s;
    s += v;
  }
  sd[t] = s;
  __syncthreads();
  for (int off = 1; off < 256; off <<= 1) {
    int x = (t >= off) ? sd[t - off] : 0;
    __syncthreads();
    sd[t] += x;
    __syncthreads();
  }
  int excl = sd[t] - s;
#pragma unroll
  for (int j = 0; j < 9; ++j) {
    int idx = t * 9 + j;
    if (idx < n) aux[idx] = excl + loc[j];
  }
}

__global__ void k_scan3(int* __restrict__ data, const int* __restrict__ aux, int n) {
  int i = blockIdx.x * 256 + threadIdx.x;
  if (i < n) data[i] += aux[i >> 10];
}

// ------- bin pass: block-local bucket sort into block-major regions ---------
// rec pack: src(17b)<<13 | (dst&255)<<5 | rel(5b). Also writes ioffs[NN]=NE.
__global__ void __launch_bounds__(256) k_bin(const int* __restrict__ src,
                                             const int* __restrict__ dst,
                                             const int* __restrict__ et,
                                             int* __restrict__ binbuf,
                                             int* __restrict__ bcnt,
                                             int* __restrict__ segoff,
                                             int* __restrict__ ioffs) {
  __shared__ int sA[512], sB[512];
  int g = blockIdx.x, t = threadIdx.x;
  if (g == 0 && t == 0) ioffs[NN] = NE;   // endcap (scan finished upstream)
  int e0 = g * EPB;
  int e1 = e0 + EPB; if (e1 > NE) e1 = NE;
  sA[t] = 0; sA[t + 256] = 0;
  __syncthreads();
  for (int e = e0 + t; e < e1; e += 256) atomicAdd(&sA[dst[e] >> 8], 1);
  __syncthreads();
  for (int b = t; b < NBKT; b += 256) bcnt[g * NBKT + b] = sA[b];
  int* pa = sA; int* pb = sB;
  for (int off = 1; off < 512; off <<= 1) {
    __syncthreads();
    for (int idx = t; idx < 512; idx += 256) {
      int v = pa[idx];
      if (idx >= off) v += pa[idx - off];
      pb[idx] = v;
    }
    int* tmp = pa; pa = pb; pb = tmp;
  }
  __syncthreads();
  for (int b = t; b < NBKT; b += 256) {
    int ex = b ? pa[b - 1] : 0;
    segoff[g * NBKT + b] = e0 + ex;
    pb[b] = ex;
  }
  __syncthreads();
  for (int e = e0 + t; e < e1; e += 256) {
    int d = dst[e];
    int pos = atomicAdd(&pb[d >> 8], 1);
    binbuf[e0 + pos] = (src[e] << 13) | ((d & 255) << 5) | et[e];
  }
}

// ------- bucket pass: block per bucket, scatter to final CSR positions ------
__global__ void __launch_bounds__(256) k_bsort(const int* __restrict__ binbuf,
                                               const int* __restrict__ bcnt,
                                               const int* __restrict__ segoff,
                                               const int* __restrict__ ioffs,
                                               int* __restrict__ es) {
  __shared__ int cur[256];
  __shared__ int scnt[NBB], ssof[NBB];
  int b = blockIdx.x, t = threadIdx.x;
  int node = b * 256 + t;
  cur[t] = (node < NN) ? ioffs[node] : 0;
  for (int g = t; g < NBB; g += 256) {
    scnt[g] = bcnt[g * NBKT + b];
    ssof[g] = segoff[g * NBKT + b];
  }
  __syncthreads();
  int w = t >> 6, l = t & 63;
  for (int g = w; g < NBB; g += 4) {
    int c = scnt[g], so = ssof[g];
    for (int base = l; base < c; base += 64) {
      int v = binbuf[so + base];
      int j = (v >> 5) & 255;
      int pos = atomicAdd(&cur[j], 1);
      es[pos] = ((v >> 13) << 5) | (v & 31);
    }
  }
}

// --------- prep: x->bf16 cast + B-fragment precompute (merged) --------------
// Bfrag[ks 0..8][ot 0..1][lane 0..63][j 0..7] bf16; lane holds B[(lane>>4)*8+j][lane&15].
__global__ void k_prep(const float* __restrict__ x, unsigned short* __restrict__ xb,
                       const float* __restrict__ V1, const float* __restrict__ lp1,
                       const float* __restrict__ V2, const float* __restrict__ lp2,
                       unsigned short* __restrict__ Bf1, unsigned short* __restrict__ Bf2) {
  int t = blockIdx.x * 256 + threadIdx.x;
  if (t < (NN * FD) / 8) {
    const float4* xp = reinterpret_cast<const float4*>(x) + t * 2;
    float4 a = xp[0], b = xp[1];
    short8 v;
    v[0] = (short)f2bf(a.x); v[1] = (short)f2bf(a.y);
    v[2] = (short)f2bf(a.z); v[3] = (short)f2bf(a.w);
    v[4] = (short)f2bf(b.x); v[5] = (short)f2bf(b.y);
    v[6] = (short)f2bf(b.z); v[7] = (short)f2bf(b.w);
    reinterpret_cast<short8*>(xb)[t] = v;
  }
  if (t < 2 * 9216) {
    int layer = t / 9216;
    int idx = t - layer * 9216;
    int kstep = idx >> 10;
    int rem = idx & 1023;
    int otile = rem >> 9;
    int li = (rem >> 3) & 63;
    int j = idx & 7;
    int k = kstep * 32 + ((li >> 4) << 3) + j;
    int o = otile * 16 + (li & 15);
    const float* V = layer ? V2 : V1;
    const float* lp = layer ? lp2 : lp1;
    float val = (k < 256) ? V[k * 32 + o] : lp[(k - 256) * 32 + o];
    (layer ? Bf2 : Bf1)[idx] = f2bf(val);
  }
}

// ---------------- fused layer: CSR aggregate (dual-stream) + MFMA finish ----
// Block = 256 thr = 4 waves = 64 nodes; wave owns 16 nodes (rows in its
// private 8 KB LDS slice). Phase 1: per node-pair dual-stream gather/FMA into
// regs, rows stored bf16 to LDS with XOR swizzle on byte bits 4-6. Phase 2:
// wave MFMA-finishes its own 16-row tile (no barrier: wave-coherent LDS).
__global__ void __launch_bounds__(256) k_layer(
    const unsigned short* __restrict__ xin,   // bf16 [NN][32]
    const int* __restrict__ ioffs,            // [NN+1]
    const int* __restrict__ es,               // CSR records src<<5|rel
    const float* __restrict__ arel,           // [20][8] fp32
    const unsigned short* __restrict__ Bfrag, // per-lane B fragments
    const float* __restrict__ bias,           // [32]
    float* __restrict__ out_f32,              // layer 2 output (or null)
    unsigned short* __restrict__ out_b16,     // layer 1 output (or null)
    int do_relu) {
  __shared__ __align__(16) unsigned short zl[64 * 256];  // 32 KB
  int t = threadIdx.x;
  int w = t >> 6, l = t & 63;
  int i = l & 31, hh = l >> 5;
  int nb = blockIdx.x * 64 + w * 16;        // wave's 16-node base
  const float4* aT = reinterpret_cast<const float4*>(arel);
  unsigned short* zw = zl + (w << 12);      // wave slice: 16 rows x 256

  // ---- phase 1: aggregate 16 nodes as 8 dual-stream pairs ----
  for (int p = 0; p < 8; ++p) {
    int vA = nb + 2 * p, vB = vA + 1;
    int eA = 0, eA1 = 0, eB = 0, eB1 = 0;
    if (vA < NN) { eA = ioffs[vA]; eA1 = ioffs[vA + 1]; }
    if (vB < NN) { eB = ioffs[vB]; eB1 = ioffs[vB + 1]; }
    eA  = __builtin_amdgcn_readfirstlane(eA);
    eA1 = __builtin_amdgcn_readfirstlane(eA1);
    eB  = __builtin_amdgcn_readfirstlane(eB);
    eB1 = __builtin_amdgcn_readfirstlane(eB1);
    float zA0 = 0.f, zA1 = 0.f, zA2 = 0.f, zA3 = 0.f;
    float zB0 = 0.f, zB1 = 0.f, zB2 = 0.f, zB3 = 0.f;
    // fused main loop: 4 edges of A + 4 edges of B (two independent chains)
    while ((eA + 4 <= eA1) & (eB + 4 <= eB1)) {
      int a0 = es[eA], a1 = es[eA + 1], a2 = es[eA + 2], a3 = es[eA + 3];
      int b0 = es[eB], b1 = es[eB + 1], b2 = es[eB + 2], b3 = es[eB + 3];
      float xa0 = bf2f(xin[((a0 >> 5) << 5) | i]);
      float xa1 = bf2f(xin[((a1 >> 5) << 5) | i]);
      float xa2 = bf2f(xin[((a2 >> 5) << 5) | i]);
      float xa3 = bf2f(xin[((a3 >> 5) << 5) | i]);
      float xb0 = bf2f(xin[((b0 >> 5) << 5) | i]);
      float xb1 = bf2f(xin[((b1 >> 5) << 5) | i]);
      float xb2 = bf2f(xin[((b2 >> 5) << 5) | i]);
      float xb3 = bf2f(xin[((b3 >> 5) << 5) | i]);
      float4 ca0 = aT[((a0 & 31) << 1) | hh];
      float4 ca1 = aT[((a1 & 31) << 1) | hh];
      float4 ca2 = aT[((a2 & 31) << 1) | hh];
      float4 ca3 = aT[((a3 & 31) << 1) | hh];
      float4 cb0 = aT[((b0 & 31) << 1) | hh];
      float4 cb1 = aT[((b1 & 31) << 1) | hh];
      float4 cb2 = aT[((b2 & 31) << 1) | hh];
      float4 cb3 = aT[((b3 & 31) << 1) | hh];
      zA0 += ca0.x * xa0; zA1 += ca0.y * xa0; zA2 += ca0.z * xa0; zA3 += ca0.w * xa0;
      zB0 += cb0.x * xb0; zB1 += cb0.y * xb0; zB2 += cb0.z * xb0; zB3 += cb0.w * xb0;
      zA0 += ca1.x * xa1; zA1 += ca1.y * xa1; zA2 += ca1.z * xa1; zA3 += ca1.w * xa1;
      zB0 += cb1.x * xb1; zB1 += cb1.y * xb1; zB2 += cb1.z * xb1; zB3 += cb1.w * xb1;
      zA0 += ca2.x * xa2; zA1 += ca2.y * xa2; zA2 += ca2.z * xa2; zA3 += ca2.w * xa2;
      zB0 += cb2.x * xb2; zB1 += cb2.y * xb2; zB2 += cb2.z * xb2; zB3 += cb2.w * xb2;
      zA0 += ca3.x * xa3; zA1 += ca3.y * xa3; zA2 += ca3.z * xa3; zA3 += ca3.w * xa3;
      zB0 += cb3.x * xb3; zB1 += cb3.y * xb3; zB2 += cb3.z * xb3; zB3 += cb3.w * xb3;
      eA += 4; eB += 4;
    }
    while (eA + 4 <= eA1) {
      int a0 = es[eA], a1 = es[eA + 1], a2 = es[eA + 2], a3 = es[eA + 3];
      float xa0 = bf2f(xin[((a0 >> 5) << 5) | i]);
      float xa1 = bf2f(xin[((a1 >> 5) << 5) | i]);
      float xa2 = bf2f(xin[((a2 >> 5) << 5) | i]);
      float xa3 = bf2f(xin[((a3 >> 5) << 5) | i]);
      float4 ca0 = aT[((a0 & 31) << 1) | hh];
      float4 ca1 = aT[((a1 & 31) << 1) | hh];
      float4 ca2 = aT[((a2 & 31) << 1) | hh];
      float4 ca3 = aT[((a3 & 31) << 1) | hh];
      zA0 += ca0.x * xa0; zA1 += ca0.y * xa0; zA2 += ca0.z * xa0; zA3 += ca0.w * xa0;
      zA0 += ca1.x * xa1; zA1 += ca1.y * xa1; zA2 += ca1.z * xa1; zA3 += ca1.w * xa1;
      zA0 += ca2.x * xa2; zA1 += ca2.y * xa2; zA2 += ca2.z * xa2; zA3 += ca2.w * xa2;
      zA0 += ca3.x * xa3; zA1 += ca3.y * xa3; zA2 += ca3.z * xa3; zA3 += ca3.w * xa3;
      eA += 4;
    }
    while (eB + 4 <= eB1) {
      int b0 = es[eB], b1 = es[eB + 1], b2 = es[eB + 2], b3 = es[eB + 3];
      float xb0 = bf2f(xin[((b0 >> 5) << 5) | i]);
      float xb1 = bf2f(xin[((b1 >> 5) << 5) | i]);
      float xb2 = bf2f(xin[((b2 >> 5) << 5) | i]);
      float xb3 = bf2f(xin[((b3 >> 5) << 5) | i]);
      float4 cb0 = aT[((b0 & 31) << 1) | hh];
      float4 cb1 = aT[((b1 & 31) << 1) | hh];
      float4 cb2 = aT[((b2 & 31) << 1) | hh];
      float4 cb3 = aT[((b3 & 31) << 1) | hh];
      zB0 += cb0.x * xb0; zB1 += cb0.y * xb0; zB2 += cb0.z * xb0; zB3 += cb0.w * xb0;
      zB0 += cb1.x * xb1; zB1 += cb1.y * xb1; zB2 += cb1.z * xb1; zB3 += cb1.w * xb1;
      zB0 += cb2.x * xb2; zB1 += cb2.y * xb2; zB2 += cb2.z * xb2; zB3 += cb2.w * xb2;
      zB0 += cb3.x * xb3; zB1 += cb3.y * xb3; zB2 += cb3.z * xb3; zB3 += cb3.w * xb3;
      eB += 4;
    }
    for (; eA < eA1; ++eA) {
      int rec = es[eA];
      float xv = bf2f(xin[((rec >> 5) << 5) | i]);
      float4 av = aT[((rec & 31) << 1) | hh];
      zA0 += av.x * xv; zA1 += av.y * xv; zA2 += av.z * xv; zA3 += av.w * xv;
    }
    for (; eB < eB1; ++eB) {
      int rec = es[eB];
      float xv = bf2f(xin[((rec >> 5) << 5) | i]);
      float4 av = aT[((rec & 31) << 1) | hh];
      zB0 += av.x * xv; zB1 += av.y * xv; zB2 += av.z * xv; zB3 += av.w * xv;
    }
    // store rows 2p (A) and 2p+1 (B) to LDS, swizzled: byte ^= (row&7)<<4
    {
      int r = 2 * p;
      char* base = (char*)zw + (r << 9);
      int sw = (r & 7) << 4;
      int off = (hh << 8) | (i << 1);
      *(unsigned short*)(base + ((off      ) ^ sw)) = f2bf(zA0);
      *(unsigned short*)(base + ((off +  64) ^ sw)) = f2bf(zA1);
      *(unsigned short*)(base + ((off + 128) ^ sw)) = f2bf(zA2);
      *(unsigned short*)(base + ((off + 192) ^ sw)) = f2bf(zA3);
    }
    {
      int r = 2 * p + 1;
      char* base = (char*)zw + (r << 9);
      int sw = (r & 7) << 4;
      int off = (hh << 8) | (i << 1);
      *(unsigned short*)(base + ((off      ) ^ sw)) = f2bf(zB0);
      *(unsigned short*)(base + ((off +  64) ^ sw)) = f2bf(zB1);
      *(unsigned short*)(base + ((off + 128) ^ sw)) = f2bf(zB2);
      *(unsigned short*)(base + ((off + 192) ^ sw)) = f2bf(zB3);
    }
  }

  // ---- phase 2: MFMA finish of the wave's own 16-row tile ----
  int row = l & 15, kg = l >> 4;
  short8 af[9];
  {
    char* rb = (char*)zw + (row << 9);
    int sw = (row & 7) << 4;
#pragma unroll
    for (int ks = 0; ks < 8; ++ks)
      af[ks] = *(const short8*)(rb + (((ks << 6) | (kg << 4)) ^ sw));
    int nA = nb + row;
    int nAc = (nA < NN) ? nA : (NN - 1);
    af[8] = *(const short8*)(xin + ((size_t)nAc << 5) + (kg << 3));  // self-loop
  }
  const short8* Bp = reinterpret_cast<const short8*>(Bfrag);
  for (int ot = 0; ot < 2; ++ot) {
    f32x4 acc = {0.f, 0.f, 0.f, 0.f};
#pragma unroll
    for (int ks = 0; ks < 9; ++ks) {
      short8 bfv = Bp[((ks * 2 + ot) << 6) + l];
      acc = __builtin_amdgcn_mfma_f32_16x16x32_bf16(af[ks], bfv, acc, 0, 0, 0);
    }
    float bs = bias[(ot << 4) + row];
#pragma unroll
    for (int q = 0; q < 4; ++q) {
      int n = nb + (kg << 2) + q;
      if (n < NN) {
        float v = acc[q] + bs;
        if (do_relu) v = fmaxf(v, 0.f);
        size_t idx = ((size_t)n << 5) + (ot << 4) + row;
        if (out_f32) out_f32[idx] = v;
        else         out_b16[idx] = f2bf(v);
      }
    }
  }
}

// ---------------- launch ----------------------------------------------------
extern "C" void kernel_launch(void* const* d_in, const int* in_sizes, int n_in,
                              void* d_out, int out_size, void* d_ws, size_t ws_size,
                              hipStream_t stream) {
  const float* x   = (const float*)d_in[0];
  const int* src   = (const int*)d_in[1];
  const int* dst   = (const int*)d_in[2];
  const int* et    = (const int*)d_in[3];
  const float* V1  = (const float*)d_in[4];
  const float* a1  = (const float*)d_in[5];
  const float* lp1 = (const float*)d_in[6];
  const float* b1  = (const float*)d_in[7];
  const float* V2  = (const float*)d_in[8];
  const float* a2  = (const float*)d_in[9];
  const float* lp2 = (const float*)d_in[10];
  const float* b2  = (const float*)d_in[11];
  float* out = (float*)d_out;

  // workspace layout (bytes)
  char* w = (char*)d_ws;
  int* ioffs  = (int*)(w + 0);                       // 400,004 -> pad 400,128
  int* aux    = (int*)(w + 400128);                  //     392 -> pad 400,640
  int* es     = (int*)(w + 400640);                  // 6,400,000 -> 6,800,640
  int* binbuf = (int*)(w + 6800640);                 // 6,422,528 -> 13,223,168
  int* bcnt   = (int*)(w + 13223168);                // 306,544 -> pad 13,529,728
  int* segoff = (int*)(w + 13529728);                // 306,544 -> pad 13,836,288
  unsigned short* xb  = (unsigned short*)(w + 13836288); // 6,400,000 -> 20,236,288
  unsigned short* h1b = (unsigned short*)(w + 20236288); // 6,400,000 -> 26,636,288
  unsigned short* Bf1 = (unsigned short*)(w + 26636288); // 18,432 -> 26,654,720
  unsigned short* Bf2 = (unsigned short*)(w + 26654720); // 18,432 -> 26,673,152
  if (ws_size < 26673152) return;

  hipMemsetAsync(ioffs, 0, (size_t)NN * 4, stream);

  k_hist<<<(NE + 255) / 256, 256, 0, stream>>>(dst, ioffs);

  int nScanBlk = (NN + 1023) / 1024;  // 98
  k_scan1<<<nScanBlk, 256, 0, stream>>>(ioffs, aux, NN);
  k_scan2<<<1, 256, 0, stream>>>(aux, nScanBlk);
  k_scan3<<<(NN + 255) / 256, 256, 0, stream>>>(ioffs, aux, NN);

  k_bin<<<NBB, 256, 0, stream>>>(src, dst, et, binbuf, bcnt, segoff, ioffs);
  k_bsort<<<NBKT, 256, 0, stream>>>(binbuf, bcnt, segoff, ioffs, es);

  k_prep<<<(((NN * FD) / 8) + 255) / 256, 256, 0, stream>>>(x, xb, V1, lp1, V2, lp2, Bf1, Bf2);

  int nblk = (NN + 63) / 64;  // 1563
  // layer 1: xb -> h1b (bf16, relu)
  k_layer<<<nblk, 256, 0, stream>>>(xb, ioffs, es, a1, Bf1, b1, nullptr, h1b, 1);
  // layer 2: h1b -> out (fp32)
  k_layer<<<nblk, 256, 0, stream>>>(h1b, ioffs, es, a2, Bf2, b2, out, nullptr, 0);
}